// Round 5
// baseline (317.601 us; speedup 1.0000x reference)
//
#include <hip/hip_runtime.h>

typedef unsigned short UST;
typedef __attribute__((ext_vector_type(8))) short bf16x8;
typedef __attribute__((ext_vector_type(8))) unsigned short us8;
typedef __attribute__((ext_vector_type(4))) float f32x4;

__device__ __forceinline__ UST f2bf(float f) {
  union { float f; unsigned int u; } x; x.f = f;
  unsigned int r = x.u + 0x7fffu + ((x.u >> 16) & 1u);
  return (UST)(r >> 16);
}
__device__ __forceinline__ float bf2f(UST h) {
  union { unsigned int u; float f; } x; x.u = ((unsigned int)h) << 16;
  return x.f;
}

// CK-style barriers: sync_lds drains LDS ops only (NOT vmcnt) then barriers.
__device__ __forceinline__ void sync_lds() {
  asm volatile("s_waitcnt lgkmcnt(0)\n\ts_barrier" ::: "memory");
}
__device__ __forceinline__ void barrier_nowait() {
  asm volatile("s_barrier" ::: "memory");
}

// ---- fp32 -> bf16 weights: Wq,Wk,Wv packed -> Wqkv (1536x512); Wo; bqkv ----
__global__ __launch_bounds__(256) void conv_w(
    const float4* __restrict__ wq, const float4* __restrict__ wk,
    const float4* __restrict__ wv, const float4* __restrict__ wo,
    ushort4* __restrict__ oqkv, ushort4* __restrict__ owo,
    const float4* __restrict__ bq4, const float4* __restrict__ bk4,
    const float4* __restrict__ bv4, float4* __restrict__ bqkv4) {
  int i = blockIdx.x * 256 + threadIdx.x;  // 65536 float4 per matrix
  float4 v;
  v = wq[i]; oqkv[i]          = make_ushort4(f2bf(v.x), f2bf(v.y), f2bf(v.z), f2bf(v.w));
  v = wk[i]; oqkv[i + 65536]  = make_ushort4(f2bf(v.x), f2bf(v.y), f2bf(v.z), f2bf(v.w));
  v = wv[i]; oqkv[i + 131072] = make_ushort4(f2bf(v.x), f2bf(v.y), f2bf(v.z), f2bf(v.w));
  v = wo[i]; owo[i]           = make_ushort4(f2bf(v.x), f2bf(v.y), f2bf(v.z), f2bf(v.w));
  if (blockIdx.x < 2) {
    int t = blockIdx.x * 256 + threadIdx.x;
    if (t < 384) bqkv4[t] = (t < 128) ? bq4[t] : (t < 256 ? bk4[t - 128] : bv4[t - 256]);
  }
}

// ---- fused GroupNorm: stats + normalize + transposed-interleaved write -----
// Xnt layout per batch: element (n,c) at (c>>3)*8192 + n*8 + (c&7)  [bf16]
__global__ __launch_bounds__(256) void gn_fused(
    const float* __restrict__ inp, const float* __restrict__ gamma,
    const float* __restrict__ beta, UST* __restrict__ Xnt) {
  const int g = blockIdx.x & 31, b = blockIdx.x >> 5;
  const int tid = threadIdx.x;
  const float* base = inp + ((size_t)b * 32 + g) * 16384;
  const float4* p4 = (const float4*)base;
  float s = 0.f, ss = 0.f;
#pragma unroll
  for (int i = 0; i < 16; i++) {
    float4 t = p4[tid + i * 256];
    s += t.x + t.y + t.z + t.w;
    ss += t.x * t.x + t.y * t.y + t.z * t.z + t.w * t.w;
  }
  for (int o = 32; o >= 1; o >>= 1) { s += __shfl_xor(s, o); ss += __shfl_xor(ss, o); }
  __shared__ float red[8];
  __shared__ float mu_s, rstd_s;
  const int w = tid >> 6;
  if ((tid & 63) == 0) { red[w * 2] = s; red[w * 2 + 1] = ss; }
  __syncthreads();
  if (tid == 0) {
    float S1 = red[0] + red[2] + red[4] + red[6];
    float S2 = red[1] + red[3] + red[5] + red[7];
    float mu = S1 * (1.f / 16384.f);
    float var = S2 * (1.f / 16384.f) - mu * mu;
    mu_s = mu; rstd_s = rsqrtf(var + 1e-6f);
  }
  __syncthreads();
  const float mu = mu_s, rstd = rstd_s;
#pragma unroll
  for (int cc = 0; cc < 2; cc++) {
    const int ccg = g * 2 + cc;
    float sc[8], sh[8];
#pragma unroll
    for (int j = 0; j < 8; j++) {
      int ch = ccg * 8 + j;
      sc[j] = gamma[ch] * rstd;
      sh[j] = beta[ch] - mu * sc[j];
    }
#pragma unroll
    for (int i = 0; i < 4; i++) {
      const int n = tid + i * 256;
      us8 v;
#pragma unroll
      for (int j = 0; j < 8; j++) {
        float x = inp[((size_t)b * 512 + ccg * 8 + j) * 1024 + n];
        v[j] = f2bf(x * sc[j] + sh[j]);
      }
      *(us8*)(Xnt + (size_t)b * 524288 + (size_t)ccg * 8192 + (size_t)n * 8) = v;
    }
  }
}

// ---- row softmax on bf16 scores: S(16384x1024) bf16 -> P bf16 --------------
__global__ __launch_bounds__(256) void softmax_k(const UST* __restrict__ S,
                                                 UST* __restrict__ P) {
  const int w = threadIdx.x >> 6, lane = threadIdx.x & 63;
  const size_t row = (size_t)blockIdx.x * 4 + w;
  const us8* Sr = (const us8*)(S + row * 1024);
  us8 a = Sr[lane], b = Sr[64 + lane];
  float v[16];
#pragma unroll
  for (int j = 0; j < 8; j++) { v[j] = bf2f(a[j]); v[8 + j] = bf2f(b[j]); }
  float m = v[0];
#pragma unroll
  for (int i = 1; i < 16; i++) m = fmaxf(m, v[i]);
#pragma unroll
  for (int o = 32; o >= 1; o >>= 1) m = fmaxf(m, __shfl_xor(m, o));
  float s = 0.f;
#pragma unroll
  for (int i = 0; i < 16; i++) { v[i] = __expf(v[i] - m); s += v[i]; }
#pragma unroll
  for (int o = 32; o >= 1; o >>= 1) s += __shfl_xor(s, o);
  const float rs = 1.f / s;
  us8* Pr = (us8*)(P + row * 1024);
  us8 oa, ob;
#pragma unroll
  for (int j = 0; j < 8; j++) { oa[j] = f2bf(v[j] * rs); ob[j] = f2bf(v[8 + j] * rs); }
  Pr[lane] = oa; Pr[64 + lane] = ob;
}

// ---- gemm_bt: C[i][j] = sum_k A[i][k]*B[j][k] -------------------------------
// A staged in double-buffered LDS (one barrier per K-iter, vmcnt never forced
// to 0); B-fragments loaded per-lane DIRECTLY from global in MFMA layout
// (identical bytes to the verified LDS-read path), 2-iter prefetch.
// 16B chunk (row,kchunk) of operand at row*rs + kchunk*cs, advancing ss per 32-k.
// EPI 6: QKV - bf16 +bias[col]; n0<1024 -> QKt row-major; n0>=1024 -> V
//        transposed into (c,m) layout (V base via `extra`, z-stride 524288)
// EPI 5: bf16 *scale | EPI 3: bf16 | EPI 4: f32 +bias[row] +extra (residual)
template <int EPI>
__global__ __launch_bounds__(256, 2) void gemm_bt(
    const UST* __restrict__ A, const UST* __restrict__ B, void* __restrict__ C,
    const float* __restrict__ bias, const float* __restrict__ extra, float scale,
    int K, int ldc,
    int rsA, int csA, int ssA, int rsB, int csB, int ssB,
    long zA, long zB, long zC) {
  // 20480 B: A dbuf = 2 x (128 rows x 40 UST); epilogue sub-tiles alias it.
  __shared__ __align__(16) UST buf[10240];
  UST* buf0 = buf;
  UST* buf1 = buf + 5120;

  const int tid = threadIdx.x;
  const int z = blockIdx.z;
  const int m0 = blockIdx.y * 128;
  const int n0 = blockIdx.x * 128;
  const UST* Ab = A + (long)z * zA;
  const UST* Bb = B + (long)z * zB;

  const int w = tid >> 6, lane = tid & 63;
  const int quad = lane >> 4, l16 = lane & 15;
  const int wm = w >> 1, wn = w & 1;  // 2x2 waves, each 64x64

  f32x4 acc[4][4];
#pragma unroll
  for (int i = 0; i < 4; i++)
#pragma unroll
    for (int j = 0; j < 4; j++) acc[i][j] = f32x4{0.f, 0.f, 0.f, 0.f};

  const int rowa = tid >> 2;   // 0..63
  const int kchunk = tid & 3;  // 8-elem chunk within 32-k step
  const UST* gA = Ab + (size_t)(m0 + rowa) * rsA + (size_t)kchunk * csA;
  const size_t a64 = (size_t)64 * rsA;
  const int lw = rowa * 40 + kchunk * 8;  // LDS write offset (UST)

  // per-lane B-fragment base: row = n0 + wn*64 + j*16 + l16, kchunk = quad
  const UST* gBf = Bb + (size_t)(n0 + wn * 64 + l16) * rsB + (size_t)quad * csB;
  const size_t b16 = (size_t)16 * rsB;

  const int nk = K >> 5;

  bf16x8 bcur[4], bnxt[4];
#pragma unroll
  for (int j = 0; j < 4; j++) bcur[j] = *(const bf16x8*)(gBf + j * b16);
  {
    const UST* g1 = gBf + (size_t)(nk > 1 ? 1 : 0) * ssB;
#pragma unroll
    for (int j = 0; j < 4; j++) bnxt[j] = *(const bf16x8*)(g1 + j * b16);
  }

  // preload + stage A tile 0 into buf0
  us8 pa0 = *(const us8*)gA;
  us8 pa1 = *(const us8*)(gA + a64);
  *(us8*)(buf0 + lw) = pa0;
  *(us8*)(buf0 + lw + 2560) = pa1;
  if (nk > 1) { gA += ssA; pa0 = *(const us8*)gA; pa1 = *(const us8*)(gA + a64); }
  sync_lds();

  for (int k = 0; k < nk; ++k) {
    UST* cur = (k & 1) ? buf1 : buf0;
    UST* nxt = (k & 1) ? buf0 : buf1;
    bf16x8 af[4];
#pragma unroll
    for (int i = 0; i < 4; i++)
      af[i] = *(const bf16x8*)(cur + (wm * 64 + i * 16 + l16) * 40 + quad * 8);
    bf16x8 b2[4];
    if (k + 2 < nk) {
      const UST* g2 = gBf + (size_t)(k + 2) * ssB;
#pragma unroll
      for (int j = 0; j < 4; j++) b2[j] = *(const bf16x8*)(g2 + j * b16);
    }
    if (k + 1 < nk) {
      *(us8*)(nxt + lw) = pa0;
      *(us8*)(nxt + lw + 2560) = pa1;
      if (k + 2 < nk) { gA += ssA; pa0 = *(const us8*)gA; pa1 = *(const us8*)(gA + a64); }
    }
#pragma unroll
    for (int i = 0; i < 4; i++)
#pragma unroll
      for (int j = 0; j < 4; j++)
        acc[i][j] = __builtin_amdgcn_mfma_f32_16x16x32_bf16(af[i], bcur[j], acc[i][j], 0, 0, 0);
    sync_lds();  // all waves: reads of cur drained, writes of nxt visible
#pragma unroll
    for (int j = 0; j < 4; j++) { bcur[j] = bnxt[j]; bnxt[j] = b2[j]; }
  }
  // final sync_lds doubles as the pre-epilogue barrier (staging -> C-tile reuse)

  // C/D layout (verified m89/m91): col = lane&15, row = quad*4 + reg
  if constexpr (EPI == 4) {
    // fp32 out + bias[row] + residual; four 32-row x 132-float phases (16.9 KB)
    float* fbuf = (float*)buf;
    float* Cb = (float*)C + (long)z * zC;
    const float* Eb = extra + (long)z * zC;
#pragma unroll
    for (int p = 0; p < 4; ++p) {
      if (p) barrier_nowait();
      if (wm == (p >> 1)) {
#pragma unroll
        for (int ii = 0; ii < 2; ii++) {
          const int i = (p & 1) * 2 + ii;
#pragma unroll
          for (int j = 0; j < 4; j++)
#pragma unroll
            for (int r = 0; r < 4; r++)
              fbuf[(ii * 16 + quad * 4 + r) * 132 + wn * 64 + j * 16 + l16] = acc[i][j][r];
        }
      }
      sync_lds();
#pragma unroll
      for (int it = 0; it < 4; ++it) {
        int q = tid + it * 256;            // 0..1023
        int row = q >> 5, colc = q & 31;   // 32 rows x 32 float4
        int gr = m0 + p * 32 + row;
        size_t off = (size_t)gr * ldc + n0 + colc * 4;
        float4 v = *(float4*)&fbuf[row * 132 + colc * 4];
        float4 e = *(const float4*)&Eb[off];
        float bb = bias[gr];
        v.x += bb + e.x; v.y += bb + e.y; v.z += bb + e.z; v.w += bb + e.w;
        *(float4*)&Cb[off] = v;
      }
    }
  } else {
    const bool vreg = (EPI == 6) && (n0 >= 1024);
    if (!vreg) {
      // bf16 row-major tile in two 64-row x 136-UST phases (17.4 KB)
      UST* Cb = (UST*)C + (long)z * zC;
#pragma unroll
      for (int h = 0; h < 2; ++h) {
        if (h) barrier_nowait();
        if (wm == h) {
#pragma unroll
          for (int i = 0; i < 4; i++)
#pragma unroll
            for (int j = 0; j < 4; j++) {
              float bc = 0.f;
              if constexpr (EPI == 6) bc = bias[n0 + wn * 64 + j * 16 + l16];
#pragma unroll
              for (int r = 0; r < 4; r++) {
                float v = acc[i][j][r] + bc;
                if constexpr (EPI == 5) v *= scale;
                buf[(i * 16 + quad * 4 + r) * 136 + wn * 64 + j * 16 + l16] = f2bf(v);
              }
            }
        }
        sync_lds();
#pragma unroll
        for (int it = 0; it < 4; ++it) {
          int q = tid + it * 256;
          int row = q >> 4, colc = q & 15;  // 64 rows x 16 us8
          us8 v = *(us8*)&buf[row * 136 + colc * 8];
          *(us8*)&Cb[(size_t)(m0 + h * 64 + row) * ldc + n0 + colc * 8] = v;
        }
      }
    } else {
      // V region: transpose into (c,m); two 64-col x 136-UST phases
      UST* Vb = (UST*)extra + (long)z * 524288;
#pragma unroll
      for (int h = 0; h < 2; ++h) {
        if (h) barrier_nowait();
        if (wn == h) {
#pragma unroll
          for (int i = 0; i < 4; i++)
#pragma unroll
            for (int j = 0; j < 4; j++) {
              const float bc = bias[n0 + wn * 64 + j * 16 + l16];
#pragma unroll
              for (int r = 0; r < 4; r++) {
                float v = acc[i][j][r] + bc;
                buf[(j * 16 + l16) * 136 + wm * 64 + i * 16 + quad * 4 + r] = f2bf(v);
              }
            }
        }
        sync_lds();
#pragma unroll
        for (int it = 0; it < 4; ++it) {
          int q = tid + it * 256;
          int c = q >> 4, mc = q & 15;  // 64 channels x 16 us8 along m
          us8 v = *(us8*)&buf[c * 136 + mc * 8];
          *(us8*)&Vb[(size_t)(n0 - 1024 + h * 64 + c) * 1024 + m0 + mc * 8] = v;
        }
      }
    }
  }
}

extern "C" void kernel_launch(void* const* d_in, const int* in_sizes, int n_in,
                              void* d_out, int out_size, void* d_ws, size_t ws_size,
                              hipStream_t stream) {
  const float* inp   = (const float*)d_in[0];
  const float* gamma = (const float*)d_in[1];
  const float* beta  = (const float*)d_in[2];
  const float* Wq    = (const float*)d_in[3];
  const float* bq    = (const float*)d_in[4];
  const float* Wk    = (const float*)d_in[5];
  const float* bk    = (const float*)d_in[6];
  const float* Wv    = (const float*)d_in[7];
  const float* bv    = (const float*)d_in[8];
  const float* Wo    = (const float*)d_in[9];
  const float* bo    = (const float*)d_in[10];
  float* out = (float*)d_out;
  char* ws = (char*)d_ws;

  UST*   Xnt   = (UST*)(ws);                           // 16 MB interleaved; reused as At
  UST*   QKt   = (UST*)(ws + ((size_t)16 << 20));      // 32 MB (b,n,1024); reused as P
  UST*   V     = (UST*)(ws + ((size_t)48 << 20));      // 16 MB (b,c,m)
  UST*   S     = (UST*)(ws + ((size_t)64 << 20));      // 32 MB (b,n,m)
  float* bqkv  = (float*)(ws + ((size_t)96 << 20));    // 6 KB
  UST*   Wqkvb = (UST*)(ws + ((size_t)96 << 20) + 8192);  // 1.5 MB (1536x512)
  UST*   Wob   = Wqkvb + 786432;                       // 512 KB
  UST*   P     = QKt;
  UST*   At    = Xnt;

  conv_w<<<256, 256, 0, stream>>>(
      (const float4*)Wq, (const float4*)Wk, (const float4*)Wv, (const float4*)Wo,
      (ushort4*)Wqkvb, (ushort4*)Wob,
      (const float4*)bq, (const float4*)bk, (const float4*)bv, (float4*)bqkv);
  gn_fused<<<512, 256, 0, stream>>>(inp, gamma, beta, Xnt);

  // QKV: rows n (per batch), cols 0..1023 -> QKt ; cols 1024..1535 -> V (transposed)
  gemm_bt<6><<<dim3(12, 8, 16), 256, 0, stream>>>(
      Xnt, Wqkvb, QKt, bqkv, (const float*)V, 1.f,
      512, 1024, 8, 8192, 32768, 512, 8, 32, 524288, 0, 1048576);
  // S(b: 1024x1024) bf16 = (Q_b @ K_b^T) / sqrt(512)
  gemm_bt<5><<<dim3(8, 8, 16), 256, 0, stream>>>(
      QKt, QKt + 512, S, nullptr, nullptr, 0.04419417382415922f,
      512, 1024, 1024, 8, 32, 1024, 8, 32, 1048576, 1048576, 1048576);
  softmax_k<<<4096, 256, 0, stream>>>(S, P);
  // At(b: 1024x512) = P_b @ V_b^T
  gemm_bt<3><<<dim3(4, 8, 16), 256, 0, stream>>>(
      P, V, At, nullptr, nullptr, 1.f,
      1024, 512, 1024, 8, 32, 1024, 8, 32, 1048576, 524288, 524288);
  // out(b: 512x1024) = Wo @ At_b^T + bo[row] + inp (residual)
  gemm_bt<4><<<dim3(8, 4, 16), 256, 0, stream>>>(
      Wob, At, out, bo, inp, 1.f,
      512, 1024, 512, 8, 32, 512, 8, 32, 0, 524288, 524288);
}

// Round 6
// 240.524 us; speedup vs baseline: 1.3205x; 1.3205x over previous
//
#include <hip/hip_runtime.h>

typedef unsigned short UST;
typedef __attribute__((ext_vector_type(8))) short bf16x8;
typedef __attribute__((ext_vector_type(8))) unsigned short us8;
typedef __attribute__((ext_vector_type(4))) float f32x4;

__device__ __forceinline__ UST f2bf(float f) {
  union { float f; unsigned int u; } x; x.f = f;
  unsigned int r = x.u + 0x7fffu + ((x.u >> 16) & 1u);
  return (UST)(r >> 16);
}
__device__ __forceinline__ float bf2f(UST h) {
  union { unsigned int u; float f; } x; x.u = ((unsigned int)h) << 16;
  return x.f;
}

// CK-style barriers: sync_lds drains LDS ops only (NOT vmcnt) then barriers.
__device__ __forceinline__ void sync_lds() {
  asm volatile("s_waitcnt lgkmcnt(0)\n\ts_barrier" ::: "memory");
}
__device__ __forceinline__ void barrier_nowait() {
  asm volatile("s_barrier" ::: "memory");
}

// ---- prep: GroupNorm (blocks 0..511) + weight conversion (blocks 512..767) --
// Xnt layout per batch: element (n,c) at (c>>3)*8192 + n*8 + (c&7)  [bf16]
__global__ __launch_bounds__(256) void prep(
    const float* __restrict__ inp, const float* __restrict__ gamma,
    const float* __restrict__ beta, UST* __restrict__ Xnt,
    const float4* __restrict__ wq, const float4* __restrict__ wk,
    const float4* __restrict__ wv, const float4* __restrict__ wo,
    ushort4* __restrict__ oqkv, ushort4* __restrict__ owo,
    const float4* __restrict__ bq4, const float4* __restrict__ bk4,
    const float4* __restrict__ bv4, float4* __restrict__ bqkv4) {
  const int tid = threadIdx.x;
  if (blockIdx.x >= 512) {
    const int wb = blockIdx.x - 512;       // 0..255
    int i = wb * 256 + tid;                // 65536 float4 per matrix
    float4 v;
    v = wq[i]; oqkv[i]          = make_ushort4(f2bf(v.x), f2bf(v.y), f2bf(v.z), f2bf(v.w));
    v = wk[i]; oqkv[i + 65536]  = make_ushort4(f2bf(v.x), f2bf(v.y), f2bf(v.z), f2bf(v.w));
    v = wv[i]; oqkv[i + 131072] = make_ushort4(f2bf(v.x), f2bf(v.y), f2bf(v.z), f2bf(v.w));
    v = wo[i]; owo[i]           = make_ushort4(f2bf(v.x), f2bf(v.y), f2bf(v.z), f2bf(v.w));
    if (wb < 2) {
      int t = wb * 256 + tid;
      if (t < 384) bqkv4[t] = (t < 128) ? bq4[t] : (t < 256 ? bk4[t - 128] : bv4[t - 256]);
    }
    return;
  }
  const int g = blockIdx.x & 31, b = blockIdx.x >> 5;
  const float* base = inp + ((size_t)b * 32 + g) * 16384;
  const float4* p4 = (const float4*)base;
  float s = 0.f, ss = 0.f;
#pragma unroll
  for (int i = 0; i < 16; i++) {
    float4 t = p4[tid + i * 256];
    s += t.x + t.y + t.z + t.w;
    ss += t.x * t.x + t.y * t.y + t.z * t.z + t.w * t.w;
  }
  for (int o = 32; o >= 1; o >>= 1) { s += __shfl_xor(s, o); ss += __shfl_xor(ss, o); }
  __shared__ float red[8];
  __shared__ float mu_s, rstd_s;
  const int w = tid >> 6;
  if ((tid & 63) == 0) { red[w * 2] = s; red[w * 2 + 1] = ss; }
  __syncthreads();
  if (tid == 0) {
    float S1 = red[0] + red[2] + red[4] + red[6];
    float S2 = red[1] + red[3] + red[5] + red[7];
    float mu = S1 * (1.f / 16384.f);
    float var = S2 * (1.f / 16384.f) - mu * mu;
    mu_s = mu; rstd_s = rsqrtf(var + 1e-6f);
  }
  __syncthreads();
  const float mu = mu_s, rstd = rstd_s;
#pragma unroll
  for (int cc = 0; cc < 2; cc++) {
    const int ccg = g * 2 + cc;
    float sc[8], sh[8];
#pragma unroll
    for (int j = 0; j < 8; j++) {
      int ch = ccg * 8 + j;
      sc[j] = gamma[ch] * rstd;
      sh[j] = beta[ch] - mu * sc[j];
    }
#pragma unroll
    for (int i = 0; i < 4; i++) {
      const int n = tid + i * 256;
      us8 v;
#pragma unroll
      for (int j = 0; j < 8; j++) {
        float x = inp[((size_t)b * 512 + ccg * 8 + j) * 1024 + n];
        v[j] = f2bf(x * sc[j] + sh[j]);
      }
      *(us8*)(Xnt + (size_t)b * 524288 + (size_t)ccg * 8192 + (size_t)n * 8) = v;
    }
  }
}

// ---- row softmax on bf16 scores: S(16384x1024) bf16 -> P bf16 --------------
__global__ __launch_bounds__(256) void softmax_k(const UST* __restrict__ S,
                                                 UST* __restrict__ P) {
  const int w = threadIdx.x >> 6, lane = threadIdx.x & 63;
  const size_t row = (size_t)blockIdx.x * 4 + w;
  const us8* Sr = (const us8*)(S + row * 1024);
  us8 a = Sr[lane], b = Sr[64 + lane];
  float v[16];
#pragma unroll
  for (int j = 0; j < 8; j++) { v[j] = bf2f(a[j]); v[8 + j] = bf2f(b[j]); }
  float m = v[0];
#pragma unroll
  for (int i = 1; i < 16; i++) m = fmaxf(m, v[i]);
#pragma unroll
  for (int o = 32; o >= 1; o >>= 1) m = fmaxf(m, __shfl_xor(m, o));
  float s = 0.f;
#pragma unroll
  for (int i = 0; i < 16; i++) { v[i] = __expf(v[i] - m); s += v[i]; }
#pragma unroll
  for (int o = 32; o >= 1; o >>= 1) s += __shfl_xor(s, o);
  const float rs = 1.f / s;
  us8* Pr = (us8*)(P + row * 1024);
  us8 oa, ob;
#pragma unroll
  for (int j = 0; j < 8; j++) { oa[j] = f2bf(v[j] * rs); ob[j] = f2bf(v[8 + j] * rs); }
  Pr[lane] = oa; Pr[64 + lane] = ob;
}

// ---- gemm_bt: C[i][j] = sum_k A[i][k]*B[j][k] -------------------------------
// Fully double-buffered LDS staging (A+B), VGPR prefetch 2 iters ahead,
// ONE sync_lds per K-iter (lgkmcnt only; vmcnt never forced to 0).
// LDS rows padded to 40 UST (conflict-free frag reads).
// SWZ: XCD-aware remap for the QKV grid (12 n-tiles x 8 m-tiles x 16 batches):
//      same-A blocks land on one XCD so each A-tile is fetched ~once per XCD.
// EPI 6: QKV - bf16 +bias[col]; n0<1024 -> QKt row-major; n0>=1024 -> V
//        transposed into (c,m) layout (V base via `extra`, z-stride 524288)
// EPI 5: bf16 *scale | EPI 3: bf16 | EPI 4: f32 +bias[row] +extra (residual)
template <int EPI, bool SWZ>
__global__ __launch_bounds__(256, 2) void gemm_bt(
    const UST* __restrict__ A, const UST* __restrict__ B, void* __restrict__ C,
    const float* __restrict__ bias, const float* __restrict__ extra, float scale,
    int K, int ldc,
    int rsA, int csA, int ssA, int rsB, int csB, int ssB,
    long zA, long zB, long zC) {
  // 40 KB: two (A 5120 + B 5120) staging buffers; epilogue aliases buf.
  __shared__ __align__(16) UST buf[20480];
  UST* l0A = buf;
  UST* l0B = buf + 5120;
  UST* l1A = buf + 10240;
  UST* l1B = buf + 15360;

  const int tid = threadIdx.x;
  int m0, n0, z;
  if constexpr (SWZ) {
    // lin in [0,1536); xcd = lin&7 owns A-tiles [xcd*16, xcd*16+16)
    int lin = blockIdx.x + 12 * (blockIdx.y + 8 * blockIdx.z);
    int g = lin & 7, idx = lin >> 3;        // idx in [0,192)
    int al = idx / 12, x = idx - al * 12;   // al in [0,16)
    int at = g * 16 + al;                   // A-tile id = (z<<3)|y
    m0 = (at & 7) * 128; n0 = x * 128; z = at >> 3;
  } else {
    m0 = blockIdx.y * 128; n0 = blockIdx.x * 128; z = blockIdx.z;
  }
  const UST* Ab = A + (long)z * zA;
  const UST* Bb = B + (long)z * zB;

  const int w = tid >> 6, lane = tid & 63;
  const int quad = lane >> 4, l16 = lane & 15;
  const int wm = w >> 1, wn = w & 1;  // 2x2 waves, each 64x64

  f32x4 acc[4][4];
#pragma unroll
  for (int i = 0; i < 4; i++)
#pragma unroll
    for (int j = 0; j < 4; j++) acc[i][j] = f32x4{0.f, 0.f, 0.f, 0.f};

  const int rowa = tid >> 2;   // 0..63
  const int kchunk = tid & 3;  // 8-elem chunk within 32-k step
  const UST* gA = Ab + (size_t)(m0 + rowa) * rsA + (size_t)kchunk * csA;
  const UST* gB = Bb + (size_t)(n0 + rowa) * rsB + (size_t)kchunk * csB;
  const size_t a64 = (size_t)64 * rsA, b64 = (size_t)64 * rsB;
  const int lw = rowa * 40 + kchunk * 8;  // LDS write offset (UST)

  const int nk = K >> 5;

  // tile 0 -> regs -> buf0; prefetch tile 1 into regs
  us8 pa0 = *(const us8*)gA, pa1 = *(const us8*)(gA + a64);
  us8 pb0 = *(const us8*)gB, pb1 = *(const us8*)(gB + b64);
  *(us8*)(l0A + lw) = pa0; *(us8*)(l0A + lw + 2560) = pa1;
  *(us8*)(l0B + lw) = pb0; *(us8*)(l0B + lw + 2560) = pb1;
  if (nk > 1) {
    gA += ssA; gB += ssB;
    pa0 = *(const us8*)gA; pa1 = *(const us8*)(gA + a64);
    pb0 = *(const us8*)gB; pb1 = *(const us8*)(gB + b64);
  }
  sync_lds();

  for (int k = 0; k < nk; ++k) {
    UST* curA = (k & 1) ? l1A : l0A;
    UST* curB = (k & 1) ? l1B : l0B;
    UST* nxtA = (k & 1) ? l0A : l1A;
    UST* nxtB = (k & 1) ? l0B : l1B;
    // stage tile k+1 (regs -> LDS) into the opposite buffer
    if (k + 1 < nk) {
      *(us8*)(nxtA + lw) = pa0; *(us8*)(nxtA + lw + 2560) = pa1;
      *(us8*)(nxtB + lw) = pb0; *(us8*)(nxtB + lw + 2560) = pb1;
    }
    // prefetch tile k+2 (global -> regs); stays in flight through the MFMAs
    us8 qa0, qa1, qb0, qb1;
    if (k + 2 < nk) {
      gA += ssA; gB += ssB;
      qa0 = *(const us8*)gA; qa1 = *(const us8*)(gA + a64);
      qb0 = *(const us8*)gB; qb1 = *(const us8*)(gB + b64);
    }
    bf16x8 af[4], bfr[4];
#pragma unroll
    for (int i = 0; i < 4; i++)
      af[i] = *(const bf16x8*)(curA + (wm * 64 + i * 16 + l16) * 40 + quad * 8);
#pragma unroll
    for (int j = 0; j < 4; j++)
      bfr[j] = *(const bf16x8*)(curB + (wn * 64 + j * 16 + l16) * 40 + quad * 8);
#pragma unroll
    for (int i = 0; i < 4; i++)
#pragma unroll
      for (int j = 0; j < 4; j++)
        acc[i][j] = __builtin_amdgcn_mfma_f32_16x16x32_bf16(af[i], bfr[j], acc[i][j], 0, 0, 0);
    sync_lds();  // reads of cur drained + writes of nxt visible, all waves
    pa0 = qa0; pa1 = qa1; pb0 = qb0; pb1 = qb1;
  }
  // final sync_lds doubles as the pre-epilogue barrier (staging -> C-tile reuse)

  // C/D layout (verified m89/m91): col = lane&15, row = quad*4 + reg
  if constexpr (EPI == 4) {
    // fp32 out + bias[row] + residual; four 32-row x 132-float phases (16.9 KB)
    float* fbuf = (float*)buf;
    float* Cb = (float*)C + (long)z * zC;
    const float* Eb = extra + (long)z * zC;
#pragma unroll
    for (int p = 0; p < 4; ++p) {
      if (p) barrier_nowait();
      if (wm == (p >> 1)) {
#pragma unroll
        for (int ii = 0; ii < 2; ii++) {
          const int i = (p & 1) * 2 + ii;
#pragma unroll
          for (int j = 0; j < 4; j++)
#pragma unroll
            for (int r = 0; r < 4; r++)
              fbuf[(ii * 16 + quad * 4 + r) * 132 + wn * 64 + j * 16 + l16] = acc[i][j][r];
        }
      }
      sync_lds();
#pragma unroll
      for (int it = 0; it < 4; ++it) {
        int q = tid + it * 256;            // 0..1023
        int row = q >> 5, colc = q & 31;   // 32 rows x 32 float4
        int gr = m0 + p * 32 + row;
        size_t off = (size_t)gr * ldc + n0 + colc * 4;
        float4 v = *(float4*)&fbuf[row * 132 + colc * 4];
        float4 e = *(const float4*)&Eb[off];
        float bb = bias[gr];
        v.x += bb + e.x; v.y += bb + e.y; v.z += bb + e.z; v.w += bb + e.w;
        *(float4*)&Cb[off] = v;
      }
    }
  } else {
    const bool vreg = (EPI == 6) && (n0 >= 1024);
    if (!vreg) {
      // bf16 row-major tile in two 64-row x 136-UST phases (17.4 KB)
      UST* Cb = (UST*)C + (long)z * zC;
#pragma unroll
      for (int h = 0; h < 2; ++h) {
        if (h) barrier_nowait();
        if (wm == h) {
#pragma unroll
          for (int i = 0; i < 4; i++)
#pragma unroll
            for (int j = 0; j < 4; j++) {
              float bc = 0.f;
              if constexpr (EPI == 6) bc = bias[n0 + wn * 64 + j * 16 + l16];
#pragma unroll
              for (int r = 0; r < 4; r++) {
                float v = acc[i][j][r] + bc;
                if constexpr (EPI == 5) v *= scale;
                buf[(i * 16 + quad * 4 + r) * 136 + wn * 64 + j * 16 + l16] = f2bf(v);
              }
            }
        }
        sync_lds();
#pragma unroll
        for (int it = 0; it < 4; ++it) {
          int q = tid + it * 256;
          int row = q >> 4, colc = q & 15;  // 64 rows x 16 us8
          us8 v = *(us8*)&buf[row * 136 + colc * 8];
          *(us8*)&Cb[(size_t)(m0 + h * 64 + row) * ldc + n0 + colc * 8] = v;
        }
      }
    } else {
      // V region: transpose into (c,m); two 64-col x 136-UST phases
      UST* Vb = (UST*)extra + (long)z * 524288;
#pragma unroll
      for (int h = 0; h < 2; ++h) {
        if (h) barrier_nowait();
        if (wn == h) {
#pragma unroll
          for (int i = 0; i < 4; i++)
#pragma unroll
            for (int j = 0; j < 4; j++) {
              const float bc = bias[n0 + wn * 64 + j * 16 + l16];
#pragma unroll
              for (int r = 0; r < 4; r++) {
                float v = acc[i][j][r] + bc;
                buf[(j * 16 + l16) * 136 + wm * 64 + i * 16 + quad * 4 + r] = f2bf(v);
              }
            }
        }
        sync_lds();
#pragma unroll
        for (int it = 0; it < 4; ++it) {
          int q = tid + it * 256;
          int c = q >> 4, mc = q & 15;  // 64 channels x 16 us8 along m
          us8 v = *(us8*)&buf[c * 136 + mc * 8];
          *(us8*)&Vb[(size_t)(n0 - 1024 + h * 64 + c) * 1024 + m0 + mc * 8] = v;
        }
      }
    }
  }
}

extern "C" void kernel_launch(void* const* d_in, const int* in_sizes, int n_in,
                              void* d_out, int out_size, void* d_ws, size_t ws_size,
                              hipStream_t stream) {
  const float* inp   = (const float*)d_in[0];
  const float* gamma = (const float*)d_in[1];
  const float* beta  = (const float*)d_in[2];
  const float* Wq    = (const float*)d_in[3];
  const float* bq    = (const float*)d_in[4];
  const float* Wk    = (const float*)d_in[5];
  const float* bk    = (const float*)d_in[6];
  const float* Wv    = (const float*)d_in[7];
  const float* bv    = (const float*)d_in[8];
  const float* Wo    = (const float*)d_in[9];
  const float* bo    = (const float*)d_in[10];
  float* out = (float*)d_out;
  char* ws = (char*)d_ws;

  UST*   Xnt   = (UST*)(ws);                           // 16 MB interleaved; reused as At
  UST*   QKt   = (UST*)(ws + ((size_t)16 << 20));      // 32 MB (b,n,1024); reused as P
  UST*   V     = (UST*)(ws + ((size_t)48 << 20));      // 16 MB (b,c,m)
  UST*   S     = (UST*)(ws + ((size_t)64 << 20));      // 32 MB (b,n,m)
  float* bqkv  = (float*)(ws + ((size_t)96 << 20));    // 6 KB
  UST*   Wqkvb = (UST*)(ws + ((size_t)96 << 20) + 8192);  // 1.5 MB (1536x512)
  UST*   Wob   = Wqkvb + 786432;                       // 512 KB
  UST*   P     = QKt;
  UST*   At    = Xnt;

  prep<<<768, 256, 0, stream>>>(
      inp, gamma, beta, Xnt,
      (const float4*)Wq, (const float4*)Wk, (const float4*)Wv, (const float4*)Wo,
      (ushort4*)Wqkvb, (ushort4*)Wob,
      (const float4*)bq, (const float4*)bk, (const float4*)bv, (float4*)bqkv);

  // QKV: rows n (per batch), cols 0..1023 -> QKt ; cols 1024..1535 -> V (transposed)
  gemm_bt<6, true><<<dim3(12, 8, 16), 256, 0, stream>>>(
      Xnt, Wqkvb, QKt, bqkv, (const float*)V, 1.f,
      512, 1024, 8, 8192, 32768, 512, 8, 32, 524288, 0, 1048576);
  // S(b: 1024x1024) bf16 = (Q_b @ K_b^T) / sqrt(512)
  gemm_bt<5, false><<<dim3(8, 8, 16), 256, 0, stream>>>(
      QKt, QKt + 512, S, nullptr, nullptr, 0.04419417382415922f,
      512, 1024, 1024, 8, 32, 1024, 8, 32, 1048576, 1048576, 1048576);
  softmax_k<<<4096, 256, 0, stream>>>(S, P);
  // At(b: 1024x512) = P_b @ V_b^T
  gemm_bt<3, false><<<dim3(4, 8, 16), 256, 0, stream>>>(
      P, V, At, nullptr, nullptr, 1.f,
      1024, 512, 1024, 8, 32, 1024, 8, 32, 1048576, 524288, 524288);
  // out(b: 512x1024) = Wo @ At_b^T + bo[row] + inp (residual)
  gemm_bt<4, false><<<dim3(8, 4, 16), 256, 0, stream>>>(
      Wob, At, out, bo, inp, 1.f,
      512, 1024, 512, 8, 32, 512, 8, 32, 0, 524288, 524288);
}

// Round 7
// 224.309 us; speedup vs baseline: 1.4159x; 1.0723x over previous
//
#include <hip/hip_runtime.h>

typedef unsigned short UST;
typedef __attribute__((ext_vector_type(8))) short bf16x8;
typedef __attribute__((ext_vector_type(8))) unsigned short us8;
typedef __attribute__((ext_vector_type(4))) float f32x4;

__device__ __forceinline__ UST f2bf(float f) {
  union { float f; unsigned int u; } x; x.f = f;
  unsigned int r = x.u + 0x7fffu + ((x.u >> 16) & 1u);
  return (UST)(r >> 16);
}
__device__ __forceinline__ float bf2f(UST h) {
  union { unsigned int u; float f; } x; x.u = ((unsigned int)h) << 16;
  return x.f;
}

// CK-style barriers: sync_lds drains LDS ops only (NOT vmcnt) then barriers.
__device__ __forceinline__ void sync_lds() {
  asm volatile("s_waitcnt lgkmcnt(0)\n\ts_barrier" ::: "memory");
}
__device__ __forceinline__ void barrier_nowait() {
  asm volatile("s_barrier" ::: "memory");
}

// ---- prep: GroupNorm (0..511) + weight conversion (512..767) + zero l ------
// Xnt layout per batch: element (n,c) at (c>>3)*8192 + n*8 + (c&7)  [bf16]
__global__ __launch_bounds__(256) void prep(
    const float* __restrict__ inp, const float* __restrict__ gamma,
    const float* __restrict__ beta, UST* __restrict__ Xnt,
    const float4* __restrict__ wq, const float4* __restrict__ wk,
    const float4* __restrict__ wv, const float4* __restrict__ wo,
    ushort4* __restrict__ oqkv, ushort4* __restrict__ owo,
    const float4* __restrict__ bq4, const float4* __restrict__ bk4,
    const float4* __restrict__ bv4, float4* __restrict__ bqkv4,
    float4* __restrict__ l4) {
  const int tid = threadIdx.x;
  if (blockIdx.x >= 768) {  // zero the softmax-denominator array (16384 f32)
    int i = (blockIdx.x - 768) * 256 + tid;  // 16 blocks x 256 = 4096 float4
    l4[i] = make_float4(0.f, 0.f, 0.f, 0.f);
    return;
  }
  if (blockIdx.x >= 512) {
    const int wb = blockIdx.x - 512;       // 0..255
    int i = wb * 256 + tid;                // 65536 float4 per matrix
    float4 v;
    v = wq[i]; oqkv[i]          = make_ushort4(f2bf(v.x), f2bf(v.y), f2bf(v.z), f2bf(v.w));
    v = wk[i]; oqkv[i + 65536]  = make_ushort4(f2bf(v.x), f2bf(v.y), f2bf(v.z), f2bf(v.w));
    v = wv[i]; oqkv[i + 131072] = make_ushort4(f2bf(v.x), f2bf(v.y), f2bf(v.z), f2bf(v.w));
    v = wo[i]; owo[i]           = make_ushort4(f2bf(v.x), f2bf(v.y), f2bf(v.z), f2bf(v.w));
    if (wb < 2) {
      int t = wb * 256 + tid;
      if (t < 384) bqkv4[t] = (t < 128) ? bq4[t] : (t < 256 ? bk4[t - 128] : bv4[t - 256]);
    }
    return;
  }
  const int g = blockIdx.x & 31, b = blockIdx.x >> 5;
  const float* base = inp + ((size_t)b * 32 + g) * 16384;
  const float4* p4 = (const float4*)base;
  float s = 0.f, ss = 0.f;
#pragma unroll
  for (int i = 0; i < 16; i++) {
    float4 t = p4[tid + i * 256];
    s += t.x + t.y + t.z + t.w;
    ss += t.x * t.x + t.y * t.y + t.z * t.z + t.w * t.w;
  }
  for (int o = 32; o >= 1; o >>= 1) { s += __shfl_xor(s, o); ss += __shfl_xor(ss, o); }
  __shared__ float red[8];
  __shared__ float mu_s, rstd_s;
  const int w = tid >> 6;
  if ((tid & 63) == 0) { red[w * 2] = s; red[w * 2 + 1] = ss; }
  __syncthreads();
  if (tid == 0) {
    float S1 = red[0] + red[2] + red[4] + red[6];
    float S2 = red[1] + red[3] + red[5] + red[7];
    float mu = S1 * (1.f / 16384.f);
    float var = S2 * (1.f / 16384.f) - mu * mu;
    mu_s = mu; rstd_s = rsqrtf(var + 1e-6f);
  }
  __syncthreads();
  const float mu = mu_s, rstd = rstd_s;
#pragma unroll
  for (int cc = 0; cc < 2; cc++) {
    const int ccg = g * 2 + cc;
    float sc[8], sh[8];
#pragma unroll
    for (int j = 0; j < 8; j++) {
      int ch = ccg * 8 + j;
      sc[j] = gamma[ch] * rstd;
      sh[j] = beta[ch] - mu * sc[j];
    }
#pragma unroll
    for (int i = 0; i < 4; i++) {
      const int n = tid + i * 256;
      us8 v;
#pragma unroll
      for (int j = 0; j < 8; j++) {
        float x = inp[((size_t)b * 512 + ccg * 8 + j) * 1024 + n];
        v[j] = f2bf(x * sc[j] + sh[j]);
      }
      *(us8*)(Xnt + (size_t)b * 524288 + (size_t)ccg * 8192 + (size_t)n * 8) = v;
    }
  }
}

// ---- gemm_bt: C[i][j] = sum_k A[i][k]*B[j][k] -------------------------------
// Double-buffered LDS staging (A+B), VGPR prefetch 2 iters ahead, ONE sync_lds
// per K-iter (lgkmcnt only; vmcnt never forced to 0). Rows padded to 40 UST.
// NT>0: XCD-aware swizzle (NT = n-tiles per A-tile). Blocks sharing an A-tile
//       land on one XCD so each A-tile is fetched ~once per XCD (r6: 4x FETCH cut).
// EPI 6: QKV - bf16 +bias[col]; n0<1024 -> QKt row-major; n0>=1024 -> V
//        transposed into (c,m) layout (V base via `extra`, z-stride 524288)
// EPI 7: P = exp(acc*scale) bf16 + per-row sum atomicAdd into `extra` (l array)
// EPI 8: bf16, acc * (1/l[row]) with l via `bias`  (softmax denominator)
// EPI 4: f32 +bias[row] +extra (residual)
template <int EPI, int NT>
__global__ __launch_bounds__(256, 2) void gemm_bt(
    const UST* __restrict__ A, const UST* __restrict__ B, void* __restrict__ C,
    const float* __restrict__ bias, const float* __restrict__ extra, float scale,
    int K, int ldc,
    int rsA, int csA, int ssA, int rsB, int csB, int ssB,
    long zA, long zB, long zC) {
  // 40 KB: two (A 5120 + B 5120) staging buffers; epilogue aliases buf.
  __shared__ __align__(16) UST buf[20480];
  UST* l0A = buf;
  UST* l0B = buf + 5120;
  UST* l1A = buf + 10240;
  UST* l1B = buf + 15360;

  const int tid = threadIdx.x;
  int m0, n0, z;
  if constexpr (NT > 0) {
    int lin = blockIdx.x + NT * (blockIdx.y + gridDim.y * blockIdx.z);
    int T = gridDim.y * gridDim.z;      // total A-tiles (multiple of 8)
    int per = T >> 3;                   // A-tiles per XCD
    int g = lin & 7, idx = lin >> 3;
    int at = g * per + idx / NT;
    int x = idx % NT;
    m0 = (at % gridDim.y) * 128; z = at / gridDim.y; n0 = x * 128;
  } else {
    m0 = blockIdx.y * 128; n0 = blockIdx.x * 128; z = blockIdx.z;
  }
  const UST* Ab = A + (long)z * zA;
  const UST* Bb = B + (long)z * zB;

  const int w = tid >> 6, lane = tid & 63;
  const int quad = lane >> 4, l16 = lane & 15;
  const int wm = w >> 1, wn = w & 1;  // 2x2 waves, each 64x64

  f32x4 acc[4][4];
#pragma unroll
  for (int i = 0; i < 4; i++)
#pragma unroll
    for (int j = 0; j < 4; j++) acc[i][j] = f32x4{0.f, 0.f, 0.f, 0.f};

  const int rowa = tid >> 2;   // 0..63
  const int kchunk = tid & 3;  // 8-elem chunk within 32-k step
  const UST* gA = Ab + (size_t)(m0 + rowa) * rsA + (size_t)kchunk * csA;
  const UST* gB = Bb + (size_t)(n0 + rowa) * rsB + (size_t)kchunk * csB;
  const size_t a64 = (size_t)64 * rsA, b64 = (size_t)64 * rsB;
  const int lw = rowa * 40 + kchunk * 8;  // LDS write offset (UST)

  const int nk = K >> 5;

  // tile 0 -> regs -> buf0; prefetch tile 1 into regs
  us8 pa0 = *(const us8*)gA, pa1 = *(const us8*)(gA + a64);
  us8 pb0 = *(const us8*)gB, pb1 = *(const us8*)(gB + b64);
  *(us8*)(l0A + lw) = pa0; *(us8*)(l0A + lw + 2560) = pa1;
  *(us8*)(l0B + lw) = pb0; *(us8*)(l0B + lw + 2560) = pb1;
  if (nk > 1) {
    gA += ssA; gB += ssB;
    pa0 = *(const us8*)gA; pa1 = *(const us8*)(gA + a64);
    pb0 = *(const us8*)gB; pb1 = *(const us8*)(gB + b64);
  }
  sync_lds();

  for (int k = 0; k < nk; ++k) {
    UST* curA = (k & 1) ? l1A : l0A;
    UST* curB = (k & 1) ? l1B : l0B;
    UST* nxtA = (k & 1) ? l0A : l1A;
    UST* nxtB = (k & 1) ? l0B : l1B;
    if (k + 1 < nk) {
      *(us8*)(nxtA + lw) = pa0; *(us8*)(nxtA + lw + 2560) = pa1;
      *(us8*)(nxtB + lw) = pb0; *(us8*)(nxtB + lw + 2560) = pb1;
    }
    us8 qa0, qa1, qb0, qb1;
    if (k + 2 < nk) {
      gA += ssA; gB += ssB;
      qa0 = *(const us8*)gA; qa1 = *(const us8*)(gA + a64);
      qb0 = *(const us8*)gB; qb1 = *(const us8*)(gB + b64);
    }
    bf16x8 af[4], bfr[4];
#pragma unroll
    for (int i = 0; i < 4; i++)
      af[i] = *(const bf16x8*)(curA + (wm * 64 + i * 16 + l16) * 40 + quad * 8);
#pragma unroll
    for (int j = 0; j < 4; j++)
      bfr[j] = *(const bf16x8*)(curB + (wn * 64 + j * 16 + l16) * 40 + quad * 8);
#pragma unroll
    for (int i = 0; i < 4; i++)
#pragma unroll
      for (int j = 0; j < 4; j++)
        acc[i][j] = __builtin_amdgcn_mfma_f32_16x16x32_bf16(af[i], bfr[j], acc[i][j], 0, 0, 0);
    sync_lds();
    pa0 = qa0; pa1 = qa1; pb0 = qb0; pb1 = qb1;
  }
  // final sync_lds doubles as the pre-epilogue barrier (staging -> C-tile reuse)

  // C/D layout (verified m89/m91): col = lane&15, row = quad*4 + reg
  if constexpr (EPI == 4) {
    // fp32 out + bias[row] + residual; four 32-row x 132-float phases
    float* fbuf = (float*)buf;
    float* Cb = (float*)C + (long)z * zC;
    const float* Eb = extra + (long)z * zC;
#pragma unroll
    for (int p = 0; p < 4; ++p) {
      if (p) barrier_nowait();
      if (wm == (p >> 1)) {
#pragma unroll
        for (int ii = 0; ii < 2; ii++) {
          const int i = (p & 1) * 2 + ii;
#pragma unroll
          for (int j = 0; j < 4; j++)
#pragma unroll
            for (int r = 0; r < 4; r++)
              fbuf[(ii * 16 + quad * 4 + r) * 132 + wn * 64 + j * 16 + l16] = acc[i][j][r];
        }
      }
      sync_lds();
#pragma unroll
      for (int it = 0; it < 4; ++it) {
        int q = tid + it * 256;
        int row = q >> 5, colc = q & 31;
        int gr = m0 + p * 32 + row;
        size_t off = (size_t)gr * ldc + n0 + colc * 4;
        float4 v = *(float4*)&fbuf[row * 132 + colc * 4];
        float4 e = *(const float4*)&Eb[off];
        float bb = bias[gr];
        v.x += bb + e.x; v.y += bb + e.y; v.z += bb + e.z; v.w += bb + e.w;
        *(float4*)&Cb[off] = v;
      }
    }
  } else if constexpr (EPI == 7) {
    // P = exp(acc*scale) bf16 + per-row partial sums atomically into l
    UST* Cb = (UST*)C + (long)z * zC;
    float* lrow = (float*)extra + (long)z * 1024;
#pragma unroll
    for (int h = 0; h < 2; ++h) {
      if (h) barrier_nowait();
      if (wm == h) {
#pragma unroll
        for (int i = 0; i < 4; i++)
#pragma unroll
          for (int j = 0; j < 4; j++)
#pragma unroll
            for (int r = 0; r < 4; r++) {
              float v = __expf(acc[i][j][r] * scale);
              buf[(i * 16 + quad * 4 + r) * 136 + wn * 64 + j * 16 + l16] = f2bf(v);
            }
      }
      sync_lds();
#pragma unroll
      for (int it = 0; it < 4; ++it) {
        int q = tid + it * 256;
        int row = q >> 4, colc = q & 15;  // 64 rows x 16 us8
        us8 v = *(us8*)&buf[row * 136 + colc * 8];
        *(us8*)&Cb[(size_t)(m0 + h * 64 + row) * ldc + n0 + colc * 8] = v;
        float s = 0.f;
#pragma unroll
        for (int j = 0; j < 8; j++) s += bf2f(v[j]);
        s += __shfl_xor(s, 8); s += __shfl_xor(s, 4);
        s += __shfl_xor(s, 2); s += __shfl_xor(s, 1);
        if ((lane & 15) == 0) atomicAdd(&lrow[m0 + h * 64 + row], s);
      }
    }
  } else if constexpr (EPI == 8) {
    // At = acc / l[row]  (softmax denominator), bf16 row-major
    UST* Cb = (UST*)C + (long)z * zC;
    const float* lrow = bias + (long)z * 1024;
#pragma unroll
    for (int h = 0; h < 2; ++h) {
      if (h) barrier_nowait();
      if (wm == h) {
#pragma unroll
        for (int i = 0; i < 4; i++) {
          float rs[4];
#pragma unroll
          for (int r = 0; r < 4; r++)
            rs[r] = 1.0f / lrow[m0 + h * 64 + i * 16 + quad * 4 + r];
#pragma unroll
          for (int j = 0; j < 4; j++)
#pragma unroll
            for (int r = 0; r < 4; r++)
              buf[(i * 16 + quad * 4 + r) * 136 + wn * 64 + j * 16 + l16] =
                  f2bf(acc[i][j][r] * rs[r]);
        }
      }
      sync_lds();
#pragma unroll
      for (int it = 0; it < 4; ++it) {
        int q = tid + it * 256;
        int row = q >> 4, colc = q & 15;
        us8 v = *(us8*)&buf[row * 136 + colc * 8];
        *(us8*)&Cb[(size_t)(m0 + h * 64 + row) * ldc + n0 + colc * 8] = v;
      }
    }
  } else {  // EPI 6: QKV
    const bool vreg = (n0 >= 1024);
    if (!vreg) {
      UST* Cb = (UST*)C + (long)z * zC;
#pragma unroll
      for (int h = 0; h < 2; ++h) {
        if (h) barrier_nowait();
        if (wm == h) {
#pragma unroll
          for (int i = 0; i < 4; i++)
#pragma unroll
            for (int j = 0; j < 4; j++) {
              const float bc = bias[n0 + wn * 64 + j * 16 + l16];
#pragma unroll
              for (int r = 0; r < 4; r++)
                buf[(i * 16 + quad * 4 + r) * 136 + wn * 64 + j * 16 + l16] =
                    f2bf(acc[i][j][r] + bc);
            }
        }
        sync_lds();
#pragma unroll
        for (int it = 0; it < 4; ++it) {
          int q = tid + it * 256;
          int row = q >> 4, colc = q & 15;
          us8 v = *(us8*)&buf[row * 136 + colc * 8];
          *(us8*)&Cb[(size_t)(m0 + h * 64 + row) * ldc + n0 + colc * 8] = v;
        }
      }
    } else {
      UST* Vb = (UST*)extra + (long)z * 524288;
#pragma unroll
      for (int h = 0; h < 2; ++h) {
        if (h) barrier_nowait();
        if (wn == h) {
#pragma unroll
          for (int i = 0; i < 4; i++)
#pragma unroll
            for (int j = 0; j < 4; j++) {
              const float bc = bias[n0 + wn * 64 + j * 16 + l16];
#pragma unroll
              for (int r = 0; r < 4; r++)
                buf[(j * 16 + l16) * 136 + wm * 64 + i * 16 + quad * 4 + r] =
                    f2bf(acc[i][j][r] + bc);
            }
        }
        sync_lds();
#pragma unroll
        for (int it = 0; it < 4; ++it) {
          int q = tid + it * 256;
          int c = q >> 4, mc = q & 15;
          us8 v = *(us8*)&buf[c * 136 + mc * 8];
          *(us8*)&Vb[(size_t)(n0 - 1024 + h * 64 + c) * 1024 + m0 + mc * 8] = v;
        }
      }
    }
  }
}

extern "C" void kernel_launch(void* const* d_in, const int* in_sizes, int n_in,
                              void* d_out, int out_size, void* d_ws, size_t ws_size,
                              hipStream_t stream) {
  const float* inp   = (const float*)d_in[0];
  const float* gamma = (const float*)d_in[1];
  const float* beta  = (const float*)d_in[2];
  const float* Wq    = (const float*)d_in[3];
  const float* bq    = (const float*)d_in[4];
  const float* Wk    = (const float*)d_in[5];
  const float* bk    = (const float*)d_in[6];
  const float* Wv    = (const float*)d_in[7];
  const float* bv    = (const float*)d_in[8];
  const float* Wo    = (const float*)d_in[9];
  const float* bo    = (const float*)d_in[10];
  float* out = (float*)d_out;
  char* ws = (char*)d_ws;

  UST*   Xnt   = (UST*)(ws);                           // 16 MB interleaved; reused as At
  UST*   QKt   = (UST*)(ws + ((size_t)16 << 20));      // 32 MB (b,n,1024)
  UST*   V     = (UST*)(ws + ((size_t)48 << 20));      // 16 MB (b,c,m)
  UST*   P     = (UST*)(ws + ((size_t)64 << 20));      // 32 MB (b,n,m) = exp(S)
  float* bqkv  = (float*)(ws + ((size_t)96 << 20));    // 6 KB
  UST*   Wqkvb = (UST*)(ws + ((size_t)96 << 20) + 8192);  // 1.5 MB (1536x512)
  UST*   Wob   = Wqkvb + 786432;                       // 512 KB
  float* l     = (float*)(ws + ((size_t)100 << 20));   // 64 KB: 16 batches x 1024 rows
  UST*   At    = Xnt;

  prep<<<784, 256, 0, stream>>>(
      inp, gamma, beta, Xnt,
      (const float4*)Wq, (const float4*)Wk, (const float4*)Wv, (const float4*)Wo,
      (ushort4*)Wqkvb, (ushort4*)Wob,
      (const float4*)bq, (const float4*)bk, (const float4*)bv, (float4*)bqkv,
      (float4*)l);

  // QKV: rows n (per batch), cols 0..1023 -> QKt ; cols 1024..1535 -> V (transposed)
  gemm_bt<6, 12><<<dim3(12, 8, 16), 256, 0, stream>>>(
      Xnt, Wqkvb, QKt, bqkv, (const float*)V, 1.f,
      512, 1024, 8, 8192, 32768, 512, 8, 32, 524288, 0, 1048576);
  // P(b: 1024x1024) = exp(Q_b @ K_b^T / sqrt(512)), row sums -> l (atomic)
  gemm_bt<7, 8><<<dim3(8, 8, 16), 256, 0, stream>>>(
      QKt, QKt + 512, P, nullptr, (const float*)l, 0.04419417382415922f,
      512, 1024, 1024, 8, 32, 1024, 8, 32, 1048576, 1048576, 1048576);
  // At(b: 1024x512) = (P_b @ V_b^T) / l[row]
  gemm_bt<8, 4><<<dim3(4, 8, 16), 256, 0, stream>>>(
      P, V, At, (const float*)l, nullptr, 1.f,
      1024, 512, 1024, 8, 32, 1024, 8, 32, 1048576, 524288, 524288);
  // out(b: 512x1024) = Wo @ At_b^T + bo[row] + inp (residual)
  gemm_bt<4, 8><<<dim3(8, 4, 16), 256, 0, stream>>>(
      Wob, At, out, bo, inp, 1.f,
      512, 1024, 512, 8, 32, 512, 8, 32, 0, 524288, 524288);
}

// Round 8
// 218.687 us; speedup vs baseline: 1.4523x; 1.0257x over previous
//
#include <hip/hip_runtime.h>

typedef unsigned short UST;
typedef __attribute__((ext_vector_type(8))) short bf16x8;
typedef __attribute__((ext_vector_type(8))) unsigned short us8;
typedef __attribute__((ext_vector_type(4))) float f32x4;

__device__ __forceinline__ UST f2bf(float f) {
  union { float f; unsigned int u; } x; x.f = f;
  unsigned int r = x.u + 0x7fffu + ((x.u >> 16) & 1u);
  return (UST)(r >> 16);
}
__device__ __forceinline__ float bf2f(UST h) {
  union { unsigned int u; float f; } x; x.u = ((unsigned int)h) << 16;
  return x.f;
}

// CK-style barriers: sync_lds drains LDS ops only (NOT vmcnt) then barriers.
__device__ __forceinline__ void sync_lds() {
  asm volatile("s_waitcnt lgkmcnt(0)\n\ts_barrier" ::: "memory");
}
__device__ __forceinline__ void barrier_nowait() {
  asm volatile("s_barrier" ::: "memory");
}

// ---- prep: GroupNorm (0..511) + weight conversion (512..767) + zero l ------
// Xnt layout per batch: element (n,c) at (c>>3)*8192 + n*8 + (c&7)  [bf16]
__global__ __launch_bounds__(256) void prep(
    const float* __restrict__ inp, const float* __restrict__ gamma,
    const float* __restrict__ beta, UST* __restrict__ Xnt,
    const float4* __restrict__ wq, const float4* __restrict__ wk,
    const float4* __restrict__ wv, const float4* __restrict__ wo,
    ushort4* __restrict__ oqkv, ushort4* __restrict__ owo,
    const float4* __restrict__ bq4, const float4* __restrict__ bk4,
    const float4* __restrict__ bv4, float4* __restrict__ bqkv4,
    float4* __restrict__ l4) {
  const int tid = threadIdx.x;
  if (blockIdx.x >= 768) {  // zero the softmax-denominator array (16384 f32)
    int i = (blockIdx.x - 768) * 256 + tid;
    l4[i] = make_float4(0.f, 0.f, 0.f, 0.f);
    return;
  }
  if (blockIdx.x >= 512) {
    const int wb = blockIdx.x - 512;       // 0..255
    int i = wb * 256 + tid;                // 65536 float4 per matrix
    float4 v;
    v = wq[i]; oqkv[i]          = make_ushort4(f2bf(v.x), f2bf(v.y), f2bf(v.z), f2bf(v.w));
    v = wk[i]; oqkv[i + 65536]  = make_ushort4(f2bf(v.x), f2bf(v.y), f2bf(v.z), f2bf(v.w));
    v = wv[i]; oqkv[i + 131072] = make_ushort4(f2bf(v.x), f2bf(v.y), f2bf(v.z), f2bf(v.w));
    v = wo[i]; owo[i]           = make_ushort4(f2bf(v.x), f2bf(v.y), f2bf(v.z), f2bf(v.w));
    if (wb < 2) {
      int t = wb * 256 + tid;
      if (t < 384) bqkv4[t] = (t < 128) ? bq4[t] : (t < 256 ? bk4[t - 128] : bv4[t - 256]);
    }
    return;
  }
  const int g = blockIdx.x & 31, b = blockIdx.x >> 5;
  const float* base = inp + ((size_t)b * 32 + g) * 16384;
  const float4* p4 = (const float4*)base;
  float s = 0.f, ss = 0.f;
#pragma unroll
  for (int i = 0; i < 16; i++) {
    float4 t = p4[tid + i * 256];
    s += t.x + t.y + t.z + t.w;
    ss += t.x * t.x + t.y * t.y + t.z * t.z + t.w * t.w;
  }
  for (int o = 32; o >= 1; o >>= 1) { s += __shfl_xor(s, o); ss += __shfl_xor(ss, o); }
  __shared__ float red[8];
  __shared__ float mu_s, rstd_s;
  const int w = tid >> 6;
  if ((tid & 63) == 0) { red[w * 2] = s; red[w * 2 + 1] = ss; }
  __syncthreads();
  if (tid == 0) {
    float S1 = red[0] + red[2] + red[4] + red[6];
    float S2 = red[1] + red[3] + red[5] + red[7];
    float mu = S1 * (1.f / 16384.f);
    float var = S2 * (1.f / 16384.f) - mu * mu;
    mu_s = mu; rstd_s = rsqrtf(var + 1e-6f);
  }
  __syncthreads();
  const float mu = mu_s, rstd = rstd_s;
#pragma unroll
  for (int cc = 0; cc < 2; cc++) {
    const int ccg = g * 2 + cc;
    float sc[8], sh[8];
#pragma unroll
    for (int j = 0; j < 8; j++) {
      int ch = ccg * 8 + j;
      sc[j] = gamma[ch] * rstd;
      sh[j] = beta[ch] - mu * sc[j];
    }
#pragma unroll
    for (int i = 0; i < 4; i++) {
      const int n = tid + i * 256;
      us8 v;
#pragma unroll
      for (int j = 0; j < 8; j++) {
        float x = inp[((size_t)b * 512 + ccg * 8 + j) * 1024 + n];
        v[j] = f2bf(x * sc[j] + sh[j]);
      }
      *(us8*)(Xnt + (size_t)b * 524288 + (size_t)ccg * 8192 + (size_t)n * 8) = v;
    }
  }
}

// ---- gemm_bt: C[i][j] = sum_k A[i][k]*B[j][k] -------------------------------
// Double-buffered LDS staging (A+B), VGPR prefetch 2 iters ahead, ONE sync_lds
// per K-iter (lgkmcnt only; vmcnt never forced to 0). Rows padded to 40 UST.
// __launch_bounds__(256,4): 4 blocks/CU (LDS 4x40960 = 160 KiB exactly) — the
// K-loop is latency-bound (r7: MfmaUtil 20%, HBM 17%, LDS ~16%), TLP covers it.
// NT>0: XCD-aware swizzle (NT = n-tiles per A-tile); r6: 4x FETCH cut.
// EPI 6: QKV - bf16 +bias[col]; n0<1024 -> QKt row-major; n0>=1024 -> V
//        transposed into (c,m) layout (V base via `extra`, z-stride 524288)
// EPI 7: P = exp(acc*scale) bf16 + per-row sum atomicAdd into `extra` (l array)
// EPI 8: bf16, acc * (1/l[row]) with l via `bias`  (softmax denominator)
// EPI 4: f32 +bias[row] +extra (residual)
template <int EPI, int NT>
__global__ __launch_bounds__(256, 4) void gemm_bt(
    const UST* __restrict__ A, const UST* __restrict__ B, void* __restrict__ C,
    const float* __restrict__ bias, const float* __restrict__ extra, float scale,
    int K, int ldc,
    int rsA, int csA, int ssA, int rsB, int csB, int ssB,
    long zA, long zB, long zC) {
  // 40 KB: two (A 5120 + B 5120) staging buffers; epilogue aliases buf.
  __shared__ __align__(16) UST buf[20480];
  UST* l0A = buf;
  UST* l0B = buf + 5120;
  UST* l1A = buf + 10240;
  UST* l1B = buf + 15360;

  const int tid = threadIdx.x;
  int m0, n0, z;
  if constexpr (NT > 0) {
    int lin = blockIdx.x + NT * (blockIdx.y + gridDim.y * blockIdx.z);
    int T = gridDim.y * gridDim.z;      // total A-tiles (multiple of 8)
    int per = T >> 3;                   // A-tiles per XCD
    int g = lin & 7, idx = lin >> 3;
    int at = g * per + idx / NT;
    int x = idx % NT;
    m0 = (at % gridDim.y) * 128; z = at / gridDim.y; n0 = x * 128;
  } else {
    m0 = blockIdx.y * 128; n0 = blockIdx.x * 128; z = blockIdx.z;
  }
  const UST* Ab = A + (long)z * zA;
  const UST* Bb = B + (long)z * zB;

  const int w = tid >> 6, lane = tid & 63;
  const int quad = lane >> 4, l16 = lane & 15;
  const int wm = w >> 1, wn = w & 1;  // 2x2 waves, each 64x64

  f32x4 acc[4][4];
#pragma unroll
  for (int i = 0; i < 4; i++)
#pragma unroll
    for (int j = 0; j < 4; j++) acc[i][j] = f32x4{0.f, 0.f, 0.f, 0.f};

  const int rowa = tid >> 2;   // 0..63
  const int kchunk = tid & 3;  // 8-elem chunk within 32-k step
  const UST* gA = Ab + (size_t)(m0 + rowa) * rsA + (size_t)kchunk * csA;
  const UST* gB = Bb + (size_t)(n0 + rowa) * rsB + (size_t)kchunk * csB;
  const size_t a64 = (size_t)64 * rsA, b64 = (size_t)64 * rsB;
  const int lw = rowa * 40 + kchunk * 8;  // LDS write offset (UST)

  const int nk = K >> 5;

  // tile 0 -> regs -> buf0; prefetch tile 1 into regs
  us8 pa0 = *(const us8*)gA, pa1 = *(const us8*)(gA + a64);
  us8 pb0 = *(const us8*)gB, pb1 = *(const us8*)(gB + b64);
  *(us8*)(l0A + lw) = pa0; *(us8*)(l0A + lw + 2560) = pa1;
  *(us8*)(l0B + lw) = pb0; *(us8*)(l0B + lw + 2560) = pb1;
  if (nk > 1) {
    gA += ssA; gB += ssB;
    pa0 = *(const us8*)gA; pa1 = *(const us8*)(gA + a64);
    pb0 = *(const us8*)gB; pb1 = *(const us8*)(gB + b64);
  }
  sync_lds();

  for (int k = 0; k < nk; ++k) {
    UST* curA = (k & 1) ? l1A : l0A;
    UST* curB = (k & 1) ? l1B : l0B;
    UST* nxtA = (k & 1) ? l0A : l1A;
    UST* nxtB = (k & 1) ? l0B : l1B;
    if (k + 1 < nk) {
      *(us8*)(nxtA + lw) = pa0; *(us8*)(nxtA + lw + 2560) = pa1;
      *(us8*)(nxtB + lw) = pb0; *(us8*)(nxtB + lw + 2560) = pb1;
    }
    us8 qa0, qa1, qb0, qb1;
    if (k + 2 < nk) {
      gA += ssA; gB += ssB;
      qa0 = *(const us8*)gA; qa1 = *(const us8*)(gA + a64);
      qb0 = *(const us8*)gB; qb1 = *(const us8*)(gB + b64);
    }
    bf16x8 af[4], bfr[4];
#pragma unroll
    for (int i = 0; i < 4; i++)
      af[i] = *(const bf16x8*)(curA + (wm * 64 + i * 16 + l16) * 40 + quad * 8);
#pragma unroll
    for (int j = 0; j < 4; j++)
      bfr[j] = *(const bf16x8*)(curB + (wn * 64 + j * 16 + l16) * 40 + quad * 8);
#pragma unroll
    for (int i = 0; i < 4; i++)
#pragma unroll
      for (int j = 0; j < 4; j++)
        acc[i][j] = __builtin_amdgcn_mfma_f32_16x16x32_bf16(af[i], bfr[j], acc[i][j], 0, 0, 0);
    sync_lds();
    pa0 = qa0; pa1 = qa1; pb0 = qb0; pb1 = qb1;
  }
  // final sync_lds doubles as the pre-epilogue barrier (staging -> C-tile reuse)

  // C/D layout (verified m89/m91): col = lane&15, row = quad*4 + reg
  if constexpr (EPI == 4) {
    // fp32 out + bias[row] + residual; four 32-row x 132-float phases
    float* fbuf = (float*)buf;
    float* Cb = (float*)C + (long)z * zC;
    const float* Eb = extra + (long)z * zC;
#pragma unroll
    for (int p = 0; p < 4; ++p) {
      if (p) barrier_nowait();
      if (wm == (p >> 1)) {
#pragma unroll
        for (int ii = 0; ii < 2; ii++) {
          const int i = (p & 1) * 2 + ii;
#pragma unroll
          for (int j = 0; j < 4; j++)
#pragma unroll
            for (int r = 0; r < 4; r++)
              fbuf[(ii * 16 + quad * 4 + r) * 132 + wn * 64 + j * 16 + l16] = acc[i][j][r];
        }
      }
      sync_lds();
#pragma unroll
      for (int it = 0; it < 4; ++it) {
        int q = tid + it * 256;
        int row = q >> 5, colc = q & 31;
        int gr = m0 + p * 32 + row;
        size_t off = (size_t)gr * ldc + n0 + colc * 4;
        float4 v = *(float4*)&fbuf[row * 132 + colc * 4];
        float4 e = *(const float4*)&Eb[off];
        float bb = bias[gr];
        v.x += bb + e.x; v.y += bb + e.y; v.z += bb + e.z; v.w += bb + e.w;
        *(float4*)&Cb[off] = v;
      }
    }
  } else if constexpr (EPI == 7) {
    // P = exp(acc*scale) bf16 + per-row partial sums atomically into l
    UST* Cb = (UST*)C + (long)z * zC;
    float* lrow = (float*)extra + (long)z * 1024;
#pragma unroll
    for (int h = 0; h < 2; ++h) {
      if (h) barrier_nowait();
      if (wm == h) {
#pragma unroll
        for (int i = 0; i < 4; i++)
#pragma unroll
          for (int j = 0; j < 4; j++)
#pragma unroll
            for (int r = 0; r < 4; r++) {
              float v = __expf(acc[i][j][r] * scale);
              buf[(i * 16 + quad * 4 + r) * 136 + wn * 64 + j * 16 + l16] = f2bf(v);
            }
      }
      sync_lds();
#pragma unroll
      for (int it = 0; it < 4; ++it) {
        int q = tid + it * 256;
        int row = q >> 4, colc = q & 15;  // 64 rows x 16 us8
        us8 v = *(us8*)&buf[row * 136 + colc * 8];
        *(us8*)&Cb[(size_t)(m0 + h * 64 + row) * ldc + n0 + colc * 8] = v;
        float s = 0.f;
#pragma unroll
        for (int j = 0; j < 8; j++) s += bf2f(v[j]);
        s += __shfl_xor(s, 8); s += __shfl_xor(s, 4);
        s += __shfl_xor(s, 2); s += __shfl_xor(s, 1);
        if ((lane & 15) == 0) atomicAdd(&lrow[m0 + h * 64 + row], s);
      }
    }
  } else if constexpr (EPI == 8) {
    // At = acc / l[row]  (softmax denominator), bf16 row-major
    UST* Cb = (UST*)C + (long)z * zC;
    const float* lrow = bias + (long)z * 1024;
#pragma unroll
    for (int h = 0; h < 2; ++h) {
      if (h) barrier_nowait();
      if (wm == h) {
#pragma unroll
        for (int i = 0; i < 4; i++) {
          float rs[4];
#pragma unroll
          for (int r = 0; r < 4; r++)
            rs[r] = 1.0f / lrow[m0 + h * 64 + i * 16 + quad * 4 + r];
#pragma unroll
          for (int j = 0; j < 4; j++)
#pragma unroll
            for (int r = 0; r < 4; r++)
              buf[(i * 16 + quad * 4 + r) * 136 + wn * 64 + j * 16 + l16] =
                  f2bf(acc[i][j][r] * rs[r]);
        }
      }
      sync_lds();
#pragma unroll
      for (int it = 0; it < 4; ++it) {
        int q = tid + it * 256;
        int row = q >> 4, colc = q & 15;
        us8 v = *(us8*)&buf[row * 136 + colc * 8];
        *(us8*)&Cb[(size_t)(m0 + h * 64 + row) * ldc + n0 + colc * 8] = v;
      }
    }
  } else {  // EPI 6: QKV
    const bool vreg = (n0 >= 1024);
    if (!vreg) {
      UST* Cb = (UST*)C + (long)z * zC;
#pragma unroll
      for (int h = 0; h < 2; ++h) {
        if (h) barrier_nowait();
        if (wm == h) {
#pragma unroll
          for (int i = 0; i < 4; i++)
#pragma unroll
            for (int j = 0; j < 4; j++) {
              const float bc = bias[n0 + wn * 64 + j * 16 + l16];
#pragma unroll
              for (int r = 0; r < 4; r++)
                buf[(i * 16 + quad * 4 + r) * 136 + wn * 64 + j * 16 + l16] =
                    f2bf(acc[i][j][r] + bc);
            }
        }
        sync_lds();
#pragma unroll
        for (int it = 0; it < 4; ++it) {
          int q = tid + it * 256;
          int row = q >> 4, colc = q & 15;
          us8 v = *(us8*)&buf[row * 136 + colc * 8];
          *(us8*)&Cb[(size_t)(m0 + h * 64 + row) * ldc + n0 + colc * 8] = v;
        }
      }
    } else {
      UST* Vb = (UST*)extra + (long)z * 524288;
#pragma unroll
      for (int h = 0; h < 2; ++h) {
        if (h) barrier_nowait();
        if (wn == h) {
#pragma unroll
          for (int i = 0; i < 4; i++)
#pragma unroll
            for (int j = 0; j < 4; j++) {
              const float bc = bias[n0 + wn * 64 + j * 16 + l16];
#pragma unroll
              for (int r = 0; r < 4; r++)
                buf[(j * 16 + l16) * 136 + wm * 64 + i * 16 + quad * 4 + r] =
                    f2bf(acc[i][j][r] + bc);
            }
        }
        sync_lds();
#pragma unroll
        for (int it = 0; it < 4; ++it) {
          int q = tid + it * 256;
          int c = q >> 4, mc = q & 15;
          us8 v = *(us8*)&buf[c * 136 + mc * 8];
          *(us8*)&Vb[(size_t)(n0 - 1024 + h * 64 + c) * 1024 + m0 + mc * 8] = v;
        }
      }
    }
  }
}

extern "C" void kernel_launch(void* const* d_in, const int* in_sizes, int n_in,
                              void* d_out, int out_size, void* d_ws, size_t ws_size,
                              hipStream_t stream) {
  const float* inp   = (const float*)d_in[0];
  const float* gamma = (const float*)d_in[1];
  const float* beta  = (const float*)d_in[2];
  const float* Wq    = (const float*)d_in[3];
  const float* bq    = (const float*)d_in[4];
  const float* Wk    = (const float*)d_in[5];
  const float* bk    = (const float*)d_in[6];
  const float* Wv    = (const float*)d_in[7];
  const float* bv    = (const float*)d_in[8];
  const float* Wo    = (const float*)d_in[9];
  const float* bo    = (const float*)d_in[10];
  float* out = (float*)d_out;
  char* ws = (char*)d_ws;

  UST*   Xnt   = (UST*)(ws);                           // 16 MB interleaved; reused as At
  UST*   QKt   = (UST*)(ws + ((size_t)16 << 20));      // 32 MB (b,n,1024)
  UST*   V     = (UST*)(ws + ((size_t)48 << 20));      // 16 MB (b,c,m)
  UST*   P     = (UST*)(ws + ((size_t)64 << 20));      // 32 MB (b,n,m) = exp(S)
  float* bqkv  = (float*)(ws + ((size_t)96 << 20));    // 6 KB
  UST*   Wqkvb = (UST*)(ws + ((size_t)96 << 20) + 8192);  // 1.5 MB (1536x512)
  UST*   Wob   = Wqkvb + 786432;                       // 512 KB
  float* l     = (float*)(ws + ((size_t)100 << 20));   // 64 KB: 16 batches x 1024 rows
  UST*   At    = Xnt;

  prep<<<784, 256, 0, stream>>>(
      inp, gamma, beta, Xnt,
      (const float4*)Wq, (const float4*)Wk, (const float4*)Wv, (const float4*)Wo,
      (ushort4*)Wqkvb, (ushort4*)Wob,
      (const float4*)bq, (const float4*)bk, (const float4*)bv, (float4*)bqkv,
      (float4*)l);

  // QKV: rows n (per batch), cols 0..1023 -> QKt ; cols 1024..1535 -> V (transposed)
  gemm_bt<6, 12><<<dim3(12, 8, 16), 256, 0, stream>>>(
      Xnt, Wqkvb, QKt, bqkv, (const float*)V, 1.f,
      512, 1024, 8, 8192, 32768, 512, 8, 32, 524288, 0, 1048576);
  // P(b: 1024x1024) = exp(Q_b @ K_b^T / sqrt(512)), row sums -> l (atomic)
  gemm_bt<7, 8><<<dim3(8, 8, 16), 256, 0, stream>>>(
      QKt, QKt + 512, P, nullptr, (const float*)l, 0.04419417382415922f,
      512, 1024, 1024, 8, 32, 1024, 8, 32, 1048576, 1048576, 1048576);
  // At(b: 1024x512) = (P_b @ V_b^T) / l[row]
  gemm_bt<8, 4><<<dim3(4, 8, 16), 256, 0, stream>>>(
      P, V, At, (const float*)l, nullptr, 1.f,
      1024, 512, 1024, 8, 32, 1024, 8, 32, 1048576, 524288, 524288);
  // out(b: 512x1024) = Wo @ At_b^T + bo[row] + inp (residual)
  gemm_bt<4, 8><<<dim3(8, 4, 16), 256, 0, stream>>>(
      Wob, At, out, bo, inp, 1.f,
      512, 1024, 512, 8, 32, 512, 8, 32, 0, 524288, 524288);
}